// Round 6
// baseline (26.477 us; speedup 1.0000x reference)
//
#include <hip/hip_runtime.h>
#include <math.h>

// DRR ray-caster, round 6 = round-5 kernel (22.3 us) with EXACTLY ONE change:
// step chunks are CONTIGUOUS ranges instead of stride-8 interleaved.
// Rationale: z advances 5.1 voxels/step; a 64B z-line spans 16 voxels ~= 3
// steps, and x0/y0 persist 3-8 steps. Contiguous iteration lets a wave hit
// L1 on ~2/3 of its lines (stride-8 jumped 41 voxels -> all lines cold).
// Natural block%8 -> u-stripe XCD mapping is kept (each XCD's L2 holds one
// x-wedge of the frustum). Sample arithmetic bit-identical to r1/r5.

#define BLOCK  256
#define CHUNKS 8
#define PPB    (BLOCK / CHUNKS)   // 32 pixels per block

typedef float f32x2 __attribute__((ext_vector_type(2), aligned(4)));

__global__ __launch_bounds__(BLOCK) void drr_kernel(
    const float* __restrict__ vol,
    const float* __restrict__ rt_inv,
    const float* __restrict__ k_inv,
    const float* __restrict__ sdd_p,
    const float* __restrict__ rot_p,
    const float* __restrict__ xyz_p,
    const int*   __restrict__ width_p,
    const int*   __restrict__ nsteps_p,
    float*       __restrict__ out,
    const int npix, const int D)
{
    const int tid   = (int)threadIdx.x;
    const int slot  = tid & (PPB - 1);   // pixel slot within block
    const int chunk = tid / PPB;         // step-chunk id [0, CHUNKS)
    const int p     = (int)blockIdx.x * PPB + slot;

    float acc    = 0.0f;
    float seglen = 0.0f;

    if (p < npix) {
        const int W = *width_p;
        const int n = *nsteps_p;
        const int h = p / W;
        const int w = p - h * W;

        // ---- pose: Rodrigues(_rot), then T = P @ rt_inv ----
        const float rx = rot_p[0], ry = rot_p[1], rz = rot_p[2];
        const float th2 = rx*rx + ry*ry + rz*rz;
        const float th  = sqrtf(th2 + 1e-30f);
        const float a   = (th2 < 1e-12f) ? (1.0f - th2 * (1.0f/6.0f))  : (sinf(th) / th);
        const float b   = (th2 < 1e-12f) ? (0.5f - th2 * (1.0f/24.0f)) : ((1.0f - cosf(th)) / th2);
        float Rm[3][3];
        Rm[0][0] = 1.0f + b * (-(ry*ry + rz*rz));
        Rm[0][1] = a * (-rz) + b * (rx*ry);
        Rm[0][2] = a * ( ry) + b * (rx*rz);
        Rm[1][0] = a * ( rz) + b * (rx*ry);
        Rm[1][1] = 1.0f + b * (-(rx*rx + rz*rz));
        Rm[1][2] = a * (-rx) + b * (ry*rz);
        Rm[2][0] = a * (-ry) + b * (rx*rz);
        Rm[2][1] = a * ( rx) + b * (ry*rz);
        Rm[2][2] = 1.0f + b * (-(rx*rx + ry*ry));
        const float tv[3] = { xyz_p[0], xyz_p[1], xyz_p[2] };
        const float* M = rt_inv;
        float Rw[3][3], tw[3];
        #pragma unroll
        for (int i = 0; i < 3; ++i) {
            #pragma unroll
            for (int j = 0; j < 4; ++j) {
                float s = Rm[i][0]*M[0*4+j] + Rm[i][1]*M[1*4+j]
                        + Rm[i][2]*M[2*4+j] + tv[i]*M[3*4+j];
                if (j < 3) Rw[i][j] = s; else tw[i] = s;
            }
        }

        const float sdd = sdd_p[0];
        const float u = (float)w + 0.5f;
        const float v = (float)h + 0.5f;
        // cam = (k_inv @ [u,v,1]) * sdd
        const float cx = (k_inv[0]*u + k_inv[1]*v + k_inv[2]) * sdd;
        const float cy = (k_inv[3]*u + k_inv[4]*v + k_inv[5]) * sdd;
        const float cz = (k_inv[6]*u + k_inv[7]*v + k_inv[8]) * sdd;
        // tgt = Rw@cam + tw ; src = tw ; ray = tgt - src (keep reference order)
        const float tgx = Rw[0][0]*cx + Rw[0][1]*cy + Rw[0][2]*cz + tw[0];
        const float tgy = Rw[1][0]*cx + Rw[1][1]*cy + Rw[1][2]*cz + tw[1];
        const float tgz = Rw[2][0]*cx + Rw[2][1]*cy + Rw[2][2]*cz + tw[2];
        const float rayx = tgx - tw[0];
        const float rayy = tgy - tw[1];
        const float rayz = tgz - tw[2];
        const float fn = (float)n;
        seglen = sqrtf(rayx*rayx + rayy*rayy + rayz*rayz) / fn;

        const float c    = 0.5f * (float)(D - 1);   // 127.5
        const float dimf = (float)(D - 1);          // 255.0
        // idx_axis(alpha) = (tw + alpha*ray) + c  -> q + alpha*ray
        const float qx = tw[0] + c, qy = tw[1] + c, qz = tw[2] + c;

        // analytic alpha range where all axes are inside [0, dimf]
        float alo = -1e30f, ahi = 1e30f;
        bool empty = false;
        {
            const float qs[3] = { qx, qy, qz };
            const float rs[3] = { rayx, rayy, rayz };
            #pragma unroll
            for (int ax = 0; ax < 3; ++ax) {
                const float q = qs[ax], r = rs[ax];
                if (fabsf(r) < 1e-20f) {
                    if (q < 0.0f || q > dimf) empty = true;
                } else {
                    const float t0 = (0.0f - q) / r;
                    const float t1 = (dimf - q) / r;
                    alo = fmaxf(alo, fminf(t0, t1));
                    ahi = fminf(ahi, fmaxf(t0, t1));
                }
            }
        }

        if (!empty && alo <= ahi) {
            // step range: alpha_i = (i+0.5)/n in [alo, ahi]; widen by 1 for
            // float safety, keep the exact per-step inside check below.
            int ilo = (int)ceilf (alo * fn - 0.5f) - 1;
            int ihi = (int)floorf(ahi * fn - 0.5f) + 1;
            ilo = max(ilo, 0);
            ihi = min(ihi, n - 1);

            // THE one change vs round 5: contiguous per-chunk step range
            // (was: stride-8 interleave). Enables ~3-step L1 line reuse.
            const int count = ihi - ilo + 1;
            if (count > 0) {
                const int len = (count + CHUNKS - 1) / CHUNKS;
                const int sc  = ilo + chunk * len;
                const int ec  = min(sc + len - 1, ihi);

                const float inv_n = 1.0f / fn;
                const int DD = D * D;
                for (int i = sc; i <= ec; ++i) {
                    const float alpha = ((float)i + 0.5f) * inv_n;
                    const float px = fmaf(alpha, rayx, qx);
                    const float py = fmaf(alpha, rayy, qy);
                    const float pz = fmaf(alpha, rayz, qz);
                    const bool inside = (px >= 0.0f) & (px <= dimf)
                                      & (py >= 0.0f) & (py <= dimf)
                                      & (pz >= 0.0f) & (pz <= dimf);
                    if (!inside) continue;
                    const float fxf = floorf(px), fyf = floorf(py), fzf = floorf(pz);
                    const float fx = px - fxf, fy = py - fyf, fz = pz - fzf;
                    int x0 = min(max((int)fxf, 0), D - 2);
                    int y0 = min(max((int)fyf, 0), D - 2);
                    int z0 = min(max((int)fzf, 0), D - 2);
                    const float* b000 = vol + (size_t)x0 * DD + (size_t)y0 * D + z0;
                    const f32x2 vA = *(const f32x2*)(b000);            // c000 c001
                    const f32x2 vB = *(const f32x2*)(b000 + D);        // c010 c011
                    const f32x2 vC = *(const f32x2*)(b000 + DD);       // c100 c101
                    const f32x2 vD = *(const f32x2*)(b000 + DD + D);   // c110 c111
                    const float c00 = vA.x * (1.0f - fz) + vA.y * fz;
                    const float c01 = vB.x * (1.0f - fz) + vB.y * fz;
                    const float c10 = vC.x * (1.0f - fz) + vC.y * fz;
                    const float c11 = vD.x * (1.0f - fz) + vD.y * fz;
                    const float c0  = c00 * (1.0f - fy) + c01 * fy;
                    const float c1  = c10 * (1.0f - fy) + c11 * fy;
                    acc += c0 * (1.0f - fx) + c1 * fx;
                }
            }
        }
    }

    // reduce CHUNKS partials per pixel
    __shared__ float red[BLOCK];
    red[tid] = acc;
    __syncthreads();
    if (tid < PPB) {
        float s = 0.0f;
        #pragma unroll
        for (int k = 0; k < CHUNKS; ++k) s += red[tid + k * PPB];
        if (p < npix) out[p] = s * seglen;
    }
}

extern "C" void kernel_launch(void* const* d_in, const int* in_sizes, int n_in,
                              void* d_out, int out_size, void* d_ws, size_t ws_size,
                              hipStream_t stream) {
    const float* vol    = (const float*)d_in[0];
    const float* rt_inv = (const float*)d_in[1];
    const float* k_inv  = (const float*)d_in[2];
    const float* sdd    = (const float*)d_in[3];
    const float* rot    = (const float*)d_in[4];
    const float* xyz    = (const float*)d_in[5];
    const int*   width  = (const int*)d_in[7];
    const int*   nsteps = (const int*)d_in[8];
    float* out = (float*)d_out;

    const int npix = out_size;                       // H*W
    const int D    = (int)lround(cbrt((double)in_sizes[0]));

    const int blocks = (npix + PPB - 1) / PPB;
    drr_kernel<<<blocks, BLOCK, 0, stream>>>(
        vol, rt_inv, k_inv, sdd, rot, xyz, width, nsteps, out, npix, D);
}

// Round 7
// 22.397 us; speedup vs baseline: 1.1822x; 1.1822x over previous
//
#include <hip/hip_runtime.h>
#include <math.h>

// DRR ray-caster, round 7 = round-5 structure (22.3 us) with the z-pair
// merged gathers forced via inline asm global_load_dwordx2 (r5's aligned(4)
// ext_vector may have been split back into dword loads by the compiler --
// this round makes the 4-gathers-per-sample emission CERTAIN).
// Model under test: cost ~ gathers x distinct-lines-per-gather (~1 line/cy/CU).
// Everything else (geometry, chunking, arithmetic, sum order) is r1/r5.

#define BLOCK  256
#define CHUNKS 8
#define PPB    (BLOCK / CHUNKS)   // 32 pixels per block

typedef float f32x2 __attribute__((ext_vector_type(2)));

template <int DC>
__global__ __launch_bounds__(BLOCK) void drr_kernel(
    const float* __restrict__ vol,
    const float* __restrict__ rt_inv,
    const float* __restrict__ k_inv,
    const float* __restrict__ sdd_p,
    const float* __restrict__ rot_p,
    const float* __restrict__ xyz_p,
    const int*   __restrict__ width_p,
    const int*   __restrict__ nsteps_p,
    float*       __restrict__ out,
    const int npix, const int Drt)
{
    const int D  = (DC > 0) ? DC : Drt;
    const int DD = D * D;

    const int tid   = (int)threadIdx.x;
    const int slot  = tid & (PPB - 1);   // pixel slot within block
    const int chunk = tid / PPB;         // step-chunk id [0, CHUNKS)
    const int p     = (int)blockIdx.x * PPB + slot;

    float acc    = 0.0f;
    float seglen = 0.0f;

    if (p < npix) {
        const int W = *width_p;
        const int n = *nsteps_p;
        const int h = p / W;
        const int w = p - h * W;

        // ---- pose: Rodrigues(_rot), then T = P @ rt_inv ----
        const float rx = rot_p[0], ry = rot_p[1], rz = rot_p[2];
        const float th2 = rx*rx + ry*ry + rz*rz;
        const float th  = sqrtf(th2 + 1e-30f);
        const float a   = (th2 < 1e-12f) ? (1.0f - th2 * (1.0f/6.0f))  : (sinf(th) / th);
        const float b   = (th2 < 1e-12f) ? (0.5f - th2 * (1.0f/24.0f)) : ((1.0f - cosf(th)) / th2);
        float Rm[3][3];
        Rm[0][0] = 1.0f + b * (-(ry*ry + rz*rz));
        Rm[0][1] = a * (-rz) + b * (rx*ry);
        Rm[0][2] = a * ( ry) + b * (rx*rz);
        Rm[1][0] = a * ( rz) + b * (rx*ry);
        Rm[1][1] = 1.0f + b * (-(rx*rx + rz*rz));
        Rm[1][2] = a * (-rx) + b * (ry*rz);
        Rm[2][0] = a * (-ry) + b * (rx*rz);
        Rm[2][1] = a * ( rx) + b * (ry*rz);
        Rm[2][2] = 1.0f + b * (-(rx*rx + ry*ry));
        const float tv[3] = { xyz_p[0], xyz_p[1], xyz_p[2] };
        const float* M = rt_inv;
        float Rw[3][3], tw[3];
        #pragma unroll
        for (int i = 0; i < 3; ++i) {
            #pragma unroll
            for (int j = 0; j < 4; ++j) {
                float s = Rm[i][0]*M[0*4+j] + Rm[i][1]*M[1*4+j]
                        + Rm[i][2]*M[2*4+j] + tv[i]*M[3*4+j];
                if (j < 3) Rw[i][j] = s; else tw[i] = s;
            }
        }

        const float sdd = sdd_p[0];
        const float u = (float)w + 0.5f;
        const float v = (float)h + 0.5f;
        const float cx = (k_inv[0]*u + k_inv[1]*v + k_inv[2]) * sdd;
        const float cy = (k_inv[3]*u + k_inv[4]*v + k_inv[5]) * sdd;
        const float cz = (k_inv[6]*u + k_inv[7]*v + k_inv[8]) * sdd;
        const float tgx = Rw[0][0]*cx + Rw[0][1]*cy + Rw[0][2]*cz + tw[0];
        const float tgy = Rw[1][0]*cx + Rw[1][1]*cy + Rw[1][2]*cz + tw[1];
        const float tgz = Rw[2][0]*cx + Rw[2][1]*cy + Rw[2][2]*cz + tw[2];
        const float rayx = tgx - tw[0];
        const float rayy = tgy - tw[1];
        const float rayz = tgz - tw[2];
        const float fn = (float)n;
        seglen = sqrtf(rayx*rayx + rayy*rayy + rayz*rayz) / fn;

        const float c    = 0.5f * (float)(D - 1);   // 127.5
        const float dimf = (float)(D - 1);          // 255.0
        const float qx = tw[0] + c, qy = tw[1] + c, qz = tw[2] + c;

        // analytic alpha range where all axes are inside [0, dimf]
        float alo = -1e30f, ahi = 1e30f;
        bool empty = false;
        {
            const float qs[3] = { qx, qy, qz };
            const float rs[3] = { rayx, rayy, rayz };
            #pragma unroll
            for (int ax = 0; ax < 3; ++ax) {
                const float q = qs[ax], r = rs[ax];
                if (fabsf(r) < 1e-20f) {
                    if (q < 0.0f || q > dimf) empty = true;
                } else {
                    const float t0 = (0.0f - q) / r;
                    const float t1 = (dimf - q) / r;
                    alo = fmaxf(alo, fminf(t0, t1));
                    ahi = fminf(ahi, fmaxf(t0, t1));
                }
            }
        }

        if (!empty && alo <= ahi) {
            int ilo = (int)ceilf (alo * fn - 0.5f) - 1;
            int ihi = (int)floorf(ahi * fn - 0.5f) + 1;
            ilo = max(ilo, 0);
            ihi = min(ihi, n - 1);
            int start = ilo + ((chunk - ilo) % CHUNKS + CHUNKS) % CHUNKS;

            const float inv_n = 1.0f / fn;
            for (int i = start; i <= ihi; i += CHUNKS) {
                const float alpha = ((float)i + 0.5f) * inv_n;
                const float px = fmaf(alpha, rayx, qx);
                const float py = fmaf(alpha, rayy, qy);
                const float pz = fmaf(alpha, rayz, qz);
                const bool inside = (px >= 0.0f) & (px <= dimf)
                                  & (py >= 0.0f) & (py <= dimf)
                                  & (pz >= 0.0f) & (pz <= dimf);
                if (!inside) continue;
                const float fxf = floorf(px), fyf = floorf(py), fzf = floorf(pz);
                const float fx = px - fxf, fy = py - fyf, fz = pz - fzf;
                int x0 = min(max((int)fxf, 0), D - 2);
                int y0 = min(max((int)fyf, 0), D - 2);
                int z0 = min(max((int)fzf, 0), D - 2);
                const float* b000 = vol + (size_t)x0 * DD + (size_t)y0 * D + z0;

                f32x2 vA, vB, vC, vD;
                if (DC == 256) {
                    // two base addresses; +y row via 1024B imm offset
                    const float* aLo = b000;         // x0   plane
                    const float* aHi = b000 + DD;    // x0+1 plane
                    asm volatile("global_load_dwordx2 %0, %1, off"
                                 : "=&v"(vA) : "v"(aLo));
                    asm volatile("global_load_dwordx2 %0, %1, off offset:1024"
                                 : "=&v"(vB) : "v"(aLo));
                    asm volatile("global_load_dwordx2 %0, %1, off"
                                 : "=&v"(vC) : "v"(aHi));
                    asm volatile("global_load_dwordx2 %0, %1, off offset:1024"
                                 : "=&v"(vD) : "v"(aHi));
                    // dataflow-ordered wait: lerp below reads vA..vD, which
                    // this asm "writes"; loads precede it by same dataflow.
                    asm volatile("s_waitcnt vmcnt(0)"
                                 : "+v"(vA), "+v"(vB), "+v"(vC), "+v"(vD)
                                 :: "memory");
                    __builtin_amdgcn_sched_barrier(0);
                } else {
                    vA[0] = b000[0];        vA[1] = b000[1];
                    vB[0] = b000[D];        vB[1] = b000[D + 1];
                    vC[0] = b000[DD];       vC[1] = b000[DD + 1];
                    vD[0] = b000[DD + D];   vD[1] = b000[DD + D + 1];
                }

                const float c00 = vA[0] * (1.0f - fz) + vA[1] * fz;
                const float c01 = vB[0] * (1.0f - fz) + vB[1] * fz;
                const float c10 = vC[0] * (1.0f - fz) + vC[1] * fz;
                const float c11 = vD[0] * (1.0f - fz) + vD[1] * fz;
                const float c0  = c00 * (1.0f - fy) + c01 * fy;
                const float c1  = c10 * (1.0f - fy) + c11 * fy;
                acc += c0 * (1.0f - fx) + c1 * fx;
            }
        }
    }

    // reduce CHUNKS partials per pixel
    __shared__ float red[BLOCK];
    red[tid] = acc;
    __syncthreads();
    if (tid < PPB) {
        float s = 0.0f;
        #pragma unroll
        for (int k = 0; k < CHUNKS; ++k) s += red[tid + k * PPB];
        if (p < npix) out[p] = s * seglen;
    }
}

extern "C" void kernel_launch(void* const* d_in, const int* in_sizes, int n_in,
                              void* d_out, int out_size, void* d_ws, size_t ws_size,
                              hipStream_t stream) {
    const float* vol    = (const float*)d_in[0];
    const float* rt_inv = (const float*)d_in[1];
    const float* k_inv  = (const float*)d_in[2];
    const float* sdd    = (const float*)d_in[3];
    const float* rot    = (const float*)d_in[4];
    const float* xyz    = (const float*)d_in[5];
    const int*   width  = (const int*)d_in[7];
    const int*   nsteps = (const int*)d_in[8];
    float* out = (float*)d_out;

    const int npix = out_size;                       // H*W
    const int D    = (int)lround(cbrt((double)in_sizes[0]));

    const int blocks = (npix + PPB - 1) / PPB;
    if (D == 256) {
        drr_kernel<256><<<blocks, BLOCK, 0, stream>>>(
            vol, rt_inv, k_inv, sdd, rot, xyz, width, nsteps, out, npix, D);
    } else {
        drr_kernel<0><<<blocks, BLOCK, 0, stream>>>(
            vol, rt_inv, k_inv, sdd, rot, xyz, width, nsteps, out, npix, D);
    }
}

// Round 8
// 22.204 us; speedup vs baseline: 1.1924x; 1.0087x over previous
//
#include <hip/hip_runtime.h>
#include <math.h>

// DRR ray-caster, round 8: v-tiled step-synchronized blocks.
// Model v3 (fits r1/r2/r5/r6/r7): cost ~ sum over wave-iterations of the
// DISTINCT L1 lines touched (fill events, ~4.8 cy each); instruction count
// and per-sample latency are irrelevant (r5/r7 nulls).
// Fix: block = 32u x 8v pixel tile, one pixel/thread, all threads step
// together through consecutive steps. Per-step block footprint ~108 lines
// (7 KB) -> L1-resident; adjacent v-rows share ~70% of lines; z-lines
// persist ~3 steps. Per-CU fill events ~11.2K -> ~2.5-3K.
// Pose/ray/slab/inside/lerp arithmetic bit-identical to round 1.

#define BLOCK 256
#define TU    32           // tile width in u (= lanes per row)
#define TV    8            // tile height in v
// fallback (generic shapes) uses round-1 geometry
#define CHUNKS 8
#define PPB    (BLOCK / CHUNKS)

__device__ __forceinline__ void setup_ray(
    const float* __restrict__ rt_inv, const float* __restrict__ k_inv,
    const float sdd, const float rx, const float ry, const float rz,
    const float tvx, const float tvy, const float tvz,
    const int w, const int h, const int n, const int D,
    float& rayx, float& rayy, float& rayz, float& seglen,
    float& qx, float& qy, float& qz, int& ilo, int& ihi)
{
    const float th2 = rx*rx + ry*ry + rz*rz;
    const float th  = sqrtf(th2 + 1e-30f);
    const float a   = (th2 < 1e-12f) ? (1.0f - th2 * (1.0f/6.0f))  : (sinf(th) / th);
    const float b   = (th2 < 1e-12f) ? (0.5f - th2 * (1.0f/24.0f)) : ((1.0f - cosf(th)) / th2);
    float Rm[3][3];
    Rm[0][0] = 1.0f + b * (-(ry*ry + rz*rz));
    Rm[0][1] = a * (-rz) + b * (rx*ry);
    Rm[0][2] = a * ( ry) + b * (rx*rz);
    Rm[1][0] = a * ( rz) + b * (rx*ry);
    Rm[1][1] = 1.0f + b * (-(rx*rx + rz*rz));
    Rm[1][2] = a * (-rx) + b * (ry*rz);
    Rm[2][0] = a * (-ry) + b * (rx*rz);
    Rm[2][1] = a * ( rx) + b * (ry*rz);
    Rm[2][2] = 1.0f + b * (-(rx*rx + ry*ry));
    const float tv[3] = { tvx, tvy, tvz };
    const float* M = rt_inv;
    float Rw[3][3], tw[3];
    #pragma unroll
    for (int i = 0; i < 3; ++i) {
        #pragma unroll
        for (int j = 0; j < 4; ++j) {
            float s = Rm[i][0]*M[0*4+j] + Rm[i][1]*M[1*4+j]
                    + Rm[i][2]*M[2*4+j] + tv[i]*M[3*4+j];
            if (j < 3) Rw[i][j] = s; else tw[i] = s;
        }
    }
    const float fn = (float)n;
    const float u = (float)w + 0.5f;
    const float v = (float)h + 0.5f;
    const float cx = (k_inv[0]*u + k_inv[1]*v + k_inv[2]) * sdd;
    const float cy = (k_inv[3]*u + k_inv[4]*v + k_inv[5]) * sdd;
    const float cz = (k_inv[6]*u + k_inv[7]*v + k_inv[8]) * sdd;
    const float tgx = Rw[0][0]*cx + Rw[0][1]*cy + Rw[0][2]*cz + tw[0];
    const float tgy = Rw[1][0]*cx + Rw[1][1]*cy + Rw[1][2]*cz + tw[1];
    const float tgz = Rw[2][0]*cx + Rw[2][1]*cy + Rw[2][2]*cz + tw[2];
    rayx = tgx - tw[0];
    rayy = tgy - tw[1];
    rayz = tgz - tw[2];
    seglen = sqrtf(rayx*rayx + rayy*rayy + rayz*rayz) / fn;

    const float c    = 0.5f * (float)(D - 1);
    const float dimf = (float)(D - 1);
    qx = tw[0] + c; qy = tw[1] + c; qz = tw[2] + c;

    float alo = -1e30f, ahi = 1e30f;
    bool empty = false;
    const float qs[3] = { qx, qy, qz };
    const float rs[3] = { rayx, rayy, rayz };
    #pragma unroll
    for (int ax = 0; ax < 3; ++ax) {
        const float q = qs[ax], r = rs[ax];
        if (fabsf(r) < 1e-20f) {
            if (q < 0.0f || q > dimf) empty = true;
        } else {
            const float t0 = (0.0f - q) / r;
            const float t1 = (dimf - q) / r;
            alo = fmaxf(alo, fminf(t0, t1));
            ahi = fminf(ahi, fmaxf(t0, t1));
        }
    }
    ilo = 0; ihi = -1;
    if (!empty && alo <= ahi) {
        ilo = (int)ceilf (alo * fn - 0.5f) - 1;   // widen by 1; exact
        ihi = (int)floorf(ahi * fn - 0.5f) + 1;   // per-step check in loop
        ilo = max(ilo, 0);
        ihi = min(ihi, n - 1);
    }
}

// ---------------- main: 32u x 8v tile, one pixel/thread, synced steps ----
template <int DC>
__global__ __launch_bounds__(BLOCK) void drr_tile_kernel(
    const float* __restrict__ vol,
    const float* __restrict__ rt_inv,
    const float* __restrict__ k_inv,
    const float* __restrict__ sdd_p,
    const float* __restrict__ rot_p,
    const float* __restrict__ xyz_p,
    const int*   __restrict__ nsteps_p,
    float*       __restrict__ out,
    const int W)
{
    const int   D    = DC;
    const int   DD   = D * D;
    const float dimf = (float)(D - 1);

    const int tid = (int)threadIdx.x;
    const int bi  = (int)blockIdx.x;
    const int nbu = W / TU;                   // blocks per v-row (8 for 256)
    const int u0  = (bi % nbu) * TU;          // bi&7 -> u-octant -> XCD band
    const int v0  = (bi / nbu) * TV;
    const int w   = u0 + (tid & (TU - 1));
    const int h   = v0 + (tid >> 5);          // TU == 32

    const int n = nsteps_p[0];
    float rayx, rayy, rayz, seglen, qx, qy, qz;
    int ilo, ihi;
    setup_ray(rt_inv, k_inv, sdd_p[0], rot_p[0], rot_p[1], rot_p[2],
              xyz_p[0], xyz_p[1], xyz_p[2], w, h, n, D,
              rayx, rayy, rayz, seglen, qx, qy, qz, ilo, ihi);

    float acc = 0.0f;
    const float inv_n = 1.0f / (float)n;

    for (int i = ilo; i <= ihi; ++i) {
        const float alpha = ((float)i + 0.5f) * inv_n;
        const float px = fmaf(alpha, rayx, qx);
        const float py = fmaf(alpha, rayy, qy);
        const float pz = fmaf(alpha, rayz, qz);
        const bool inside = (px >= 0.0f) & (px <= dimf)
                          & (py >= 0.0f) & (py <= dimf)
                          & (pz >= 0.0f) & (pz <= dimf);
        const float fxf = floorf(px), fyf = floorf(py), fzf = floorf(pz);
        const float fx = px - fxf, fy = py - fyf, fz = pz - fzf;
        const int x0 = min(max((int)fxf, 0), D - 2);
        const int y0 = min(max((int)fyf, 0), D - 2);
        const int z0 = min(max((int)fzf, 0), D - 2);
        const float* b000 = vol + ((size_t)x0 * DD + (size_t)y0 * D + z0);
        const float c000 = b000[0];
        const float c001 = b000[1];
        const float c010 = b000[D];
        const float c011 = b000[D + 1];
        const float c100 = b000[DD];
        const float c101 = b000[DD + 1];
        const float c110 = b000[DD + D];
        const float c111 = b000[DD + D + 1];
        const float c00 = c000 * (1.0f - fz) + c001 * fz;
        const float c01 = c010 * (1.0f - fz) + c011 * fz;
        const float c10 = c100 * (1.0f - fz) + c101 * fz;
        const float c11 = c110 * (1.0f - fz) + c111 * fz;
        const float c0  = c00 * (1.0f - fy) + c01 * fy;
        const float c1  = c10 * (1.0f - fy) + c11 * fy;
        const float val = c0 * (1.0f - fx) + c1 * fx;
        acc += inside ? val : 0.0f;           // select, no divergent continue
    }

    out[h * W + w] = acc * seglen;
}

// ---------------- fallback: round-1 kernel (generic shapes) ---------------
__global__ __launch_bounds__(BLOCK) void drr_kernel(
    const float* __restrict__ vol,
    const float* __restrict__ rt_inv,
    const float* __restrict__ k_inv,
    const float* __restrict__ sdd_p,
    const float* __restrict__ rot_p,
    const float* __restrict__ xyz_p,
    const int*   __restrict__ width_p,
    const int*   __restrict__ nsteps_p,
    float*       __restrict__ out,
    const int npix, const int D)
{
    const int tid   = (int)threadIdx.x;
    const int slot  = tid & (PPB - 1);
    const int chunk = tid / PPB;
    const int p     = (int)blockIdx.x * PPB + slot;

    float acc    = 0.0f;
    float seglen = 0.0f;

    if (p < npix) {
        const int W = *width_p;
        const int n = *nsteps_p;
        const int h = p / W;
        const int w = p - h * W;
        float rayx, rayy, rayz, qx, qy, qz;
        int ilo, ihi;
        setup_ray(rt_inv, k_inv, sdd_p[0], rot_p[0], rot_p[1], rot_p[2],
                  xyz_p[0], xyz_p[1], xyz_p[2], w, h, n, D,
                  rayx, rayy, rayz, seglen, qx, qy, qz, ilo, ihi);
        const float dimf = (float)(D - 1);
        const float fn = (float)n;
        if (ihi >= ilo) {
            int start = ilo + ((chunk - ilo) % CHUNKS + CHUNKS) % CHUNKS;
            const float inv_n = 1.0f / fn;
            const int DD = D * D;
            for (int i = start; i <= ihi; i += CHUNKS) {
                const float alpha = ((float)i + 0.5f) * inv_n;
                const float px = fmaf(alpha, rayx, qx);
                const float py = fmaf(alpha, rayy, qy);
                const float pz = fmaf(alpha, rayz, qz);
                const bool inside = (px >= 0.0f) & (px <= dimf)
                                  & (py >= 0.0f) & (py <= dimf)
                                  & (pz >= 0.0f) & (pz <= dimf);
                if (!inside) continue;
                const float fxf = floorf(px), fyf = floorf(py), fzf = floorf(pz);
                const float fx = px - fxf, fy = py - fyf, fz = pz - fzf;
                int x0 = min(max((int)fxf, 0), D - 2);
                int y0 = min(max((int)fyf, 0), D - 2);
                int z0 = min(max((int)fzf, 0), D - 2);
                const float* b000 = vol + (size_t)x0 * DD + (size_t)y0 * D + z0;
                const float c000 = b000[0];
                const float c001 = b000[1];
                const float c010 = b000[D];
                const float c011 = b000[D + 1];
                const float c100 = b000[DD];
                const float c101 = b000[DD + 1];
                const float c110 = b000[DD + D];
                const float c111 = b000[DD + D + 1];
                const float c00 = c000 * (1.0f - fz) + c001 * fz;
                const float c01 = c010 * (1.0f - fz) + c011 * fz;
                const float c10 = c100 * (1.0f - fz) + c101 * fz;
                const float c11 = c110 * (1.0f - fz) + c111 * fz;
                const float c0  = c00 * (1.0f - fy) + c01 * fy;
                const float c1  = c10 * (1.0f - fy) + c11 * fy;
                acc += c0 * (1.0f - fx) + c1 * fx;
            }
        }
    }

    __shared__ float red[BLOCK];
    red[tid] = acc;
    __syncthreads();
    if (tid < PPB) {
        float s = 0.0f;
        #pragma unroll
        for (int k = 0; k < CHUNKS; ++k) s += red[tid + k * PPB];
        if (p < npix) out[p] = s * seglen;
    }
}

extern "C" void kernel_launch(void* const* d_in, const int* in_sizes, int n_in,
                              void* d_out, int out_size, void* d_ws, size_t ws_size,
                              hipStream_t stream) {
    const float* vol    = (const float*)d_in[0];
    const float* rt_inv = (const float*)d_in[1];
    const float* k_inv  = (const float*)d_in[2];
    const float* sdd    = (const float*)d_in[3];
    const float* rot    = (const float*)d_in[4];
    const float* xyz    = (const float*)d_in[5];
    const int*   width  = (const int*)d_in[7];
    const int*   nsteps = (const int*)d_in[8];
    float* out = (float*)d_out;

    const int npix = out_size;                       // H*W
    const int D    = (int)lround(cbrt((double)in_sizes[0]));
    const int W    = 256;                            // tile path requires 256x256

    if (D == 256 && npix == 65536) {
        const int blocks = npix / BLOCK;             // 256 blocks, 1/CU
        drr_tile_kernel<256><<<blocks, BLOCK, 0, stream>>>(
            vol, rt_inv, k_inv, sdd, rot, xyz, nsteps, out, W);
    } else {
        const int blocks = (npix + PPB - 1) / PPB;
        drr_kernel<<<blocks, BLOCK, 0, stream>>>(
            vol, rt_inv, k_inv, sdd, rot, xyz, width, nsteps, out, npix, D);
    }
}